// Round 3
// baseline (350.281 us; speedup 1.0000x reference)
//
#include <hip/hip_runtime.h>

// Problem constants (fixed by reference setup_inputs)
#define BB 32
#define DD 64
#define HH 16
#define TT 256
#define KK 512
#define NN (BB*HH*TT)          // 131072 tokens
#define HT (HH*TT)             // 4096
#define DHT (DD*HT)            // 262144
#define ZQ_SIZE (BB*DD*HH*TT)
#define COMMIT_OFF ZQ_SIZE
#define IDX_OFF (ZQ_SIZE+1)
#define PPL_OFF (IDX_OFF+NN)
#define USE_OFF (PPL_OFF+1)

// ws layout (float offsets):
#define CNT_OFF    0       // counts[512]
#define CPART_OFF  512     // per-wave commit partials[2048] (plain stores)
#define CDELTA_OFF 2560    // rescue commitment correction (float atomic)
#define RC_OFF     2561    // int rescue count
#define DONE_OFF   2562    // int gate counter for fused stats
#define RLIST_OFF  2564    // (token:int, dminA:float-bits) pairs, up to RMAX
#define RMAX       24576
#define EBH_OFF    51720   // 512x64 f16 (RNE), code-major = 16384 floats

// rescue margin on the DOT scale (fp16 single-precision screen):
// worst-case per-dot err <= 2^-10 * |z| <= 2^-10*12 = 0.0117; two dots + tag quantum
#define MARGIN_A 0.028f

using f16x8 = __attribute__((ext_vector_type(8))) _Float16;
using f32x4 = __attribute__((ext_vector_type(4))) float;

__device__ __forceinline__ f16x8 hc(uint4 v) { return __builtin_bit_cast(f16x8, v); }
__device__ __forceinline__ unsigned f16pair(float a, float b) {
    unsigned short ha = __builtin_bit_cast(unsigned short, (_Float16)a);  // RNE
    unsigned short hb = __builtin_bit_cast(unsigned short, (_Float16)b);
    return (unsigned)ha | ((unsigned)hb << 16);
}
__device__ __forceinline__ float pick4(float a0, float a1, float a2, float a3, int i) {
    float x = (i & 1) ? a1 : a0;
    float y = (i & 1) ? a3 : a2;
    return (i & 2) ? y : x;
}

// 32 blocks x 256: fp16(RNE) codebook, code-major linear; block 0 zeroes scalars.
__global__ void vq_init(const float* __restrict__ emb, float* __restrict__ ws) {
    const int tid = threadIdx.x, blk = blockIdx.x;
    if (blk == 0) {
        ws[CNT_OFF + tid] = 0.0f;
        ws[CNT_OFF + 256 + tid] = 0.0f;
        if (tid == 0) {
            ws[CDELTA_OFF] = 0.0f;
            ((int*)ws)[RC_OFF] = 0;
            ((int*)ws)[DONE_OFF] = 0;
        }
    }
    const int k  = blk * 16 + (tid >> 4);
    const int d0 = (tid & 15) * 4;
    float4 v = *reinterpret_cast<const float4*>(emb + k * DD + d0);
    uint2 w;
    w.x = f16pair(v.x, v.y);
    w.y = f16pair(v.z, v.w);
    reinterpret_cast<uint2*>(ws + EBH_OFF)[k * 16 + (d0 >> 2)] = w;
}

// Screen v4: round-0 structure (64 tokens/wave, 512 blocks x 256, LDS-staged,
// reg-prefetched B) but SINGLE fp16 MFMA per tile per K-half (2 vs 6):
// MFMA/LDS/VALU all drop ~3x below the z_e-read + z_q-write memory floor.
// Wider rescue margin (0.028 on dot scale) covers fp16 worst-case error.
__global__ __launch_bounds__(256, 2) void vq_screen(
    const float* __restrict__ z_e, const float* __restrict__ emb,
    float* __restrict__ ws, float* __restrict__ out_zq, float* __restrict__ out_idx)
{
    __shared__ uint4 sh[2304];      // 256 codes * 9 uint4 (padded) = 36,864 B
    __shared__ int hist[KK];        // + 2 KB

    const int tid  = threadIdx.x;
    const int lane = tid & 63;
    const int col  = lane & 15;
    const int q    = lane >> 4;
    const int W    = (blockIdx.x << 2) | (tid >> 6);   // global wave id, 0..2047
    const int base_tok = W * 64;

    hist[tid] = 0; hist[tid + 256] = 0;

    const uint4* eb4 = reinterpret_cast<const uint4*>(ws + EBH_OFF);

    // ---- A fragments: 4 token-tiles x 2 k-frags, fp16 RNE; + per-(s) |z|^2 partials
    f16x8 af[4][2];
    float zp[4];
#pragma unroll
    for (int s = 0; s < 4; ++s) {
        zp[s] = 0.0f;
        const int n = base_tok + s * 16 + col;
        const size_t zoff = (size_t)(n >> 12) * DHT + (size_t)((n >> 8) & 15) * 256 + (size_t)(n & 255);
#pragma unroll
        for (int kf = 0; kf < 2; ++kf) {
            const int d0 = kf * 32 + q * 8;
            unsigned hu[4];
#pragma unroll
            for (int jj = 0; jj < 4; ++jj) {
                float z0 = z_e[zoff + (size_t)(d0 + 2*jj + 0) * HT];
                float z1 = z_e[zoff + (size_t)(d0 + 2*jj + 1) * HT];
                zp[s] = fmaf(z0, z0, zp[s]);
                zp[s] = fmaf(z1, z1, zp[s]);
                hu[jj] = f16pair(z0, z1);
            }
            af[s][kf] = hc(make_uint4(hu[0], hu[1], hu[2], hu[3]));
        }
    }
    // complete per-token |z|^2 (sum over the 4 q-lanes of each col)
#pragma unroll
    for (int s = 0; s < 4; ++s) {
        zp[s] += __shfl_xor(zp[s], 16, 64);
        zp[s] += __shfl_xor(zp[s], 32, 64);
    }

    // top-2 packed-max state (code id in low 9 mantissa bits)
    float m1[4][4], m2[4][4];
#pragma unroll
    for (int s = 0; s < 4; ++s)
#pragma unroll
        for (int r = 0; r < 4; ++r) { m1[s][r] = -3.4e38f; m2[s][r] = -3.4e38f; }

    unsigned ktag = (unsigned)col;
    const int idx0 = col * 9 + q;   // this lane's uint4 row base within a code-tile

#pragma unroll
    for (int p = 0; p < 2; ++p) {
        if (p) __syncthreads();   // phase-0 reads done before overwrite
#pragma unroll
        for (int j = 0; j < 8; ++j) {
            const int local = j * 256 + tid;
            const int c = local >> 3, jj = local & 7;
            sh[c * 9 + jj] = eb4[p * 2048 + local];
        }
        __syncthreads();

        // prologue loads for ctl=0
        uint4 nh0 = sh[idx0], nh1 = sh[idx0 + 4];

#pragma unroll 4
        for (int ctl = 0; ctl < 16; ++ctl) {
            f16x8 b0 = hc(nh0), b1 = hc(nh1);
            if (ctl < 15) {   // prefetch next ctl BEFORE this ctl's MFMAs
                const int ni = idx0 + (ctl + 1) * 144;
                nh0 = sh[ni]; nh1 = sh[ni + 4];
            }
#pragma unroll
            for (int s = 0; s < 4; ++s) {
                f32x4 acc = {0.f, 0.f, 0.f, 0.f};
                acc = __builtin_amdgcn_mfma_f32_16x16x32_f16(af[s][0], b0, acc, 0, 0, 0);
                acc = __builtin_amdgcn_mfma_f32_16x16x32_f16(af[s][1], b1, acc, 0, 0, 0);
#pragma unroll
                for (int r = 0; r < 4; ++r) {
                    float pk = __uint_as_float((__float_as_uint(acc[r]) & 0xFFFFFE00u) | ktag);
                    m2[s][r] = __builtin_amdgcn_fmed3f(pk, m1[s][r], m2[s][r]);
                    m1[s][r] = fmaxf(m1[s][r], pk);
                }
            }
            ktag += 16u;
        }
    }

    // cross-lane top-2 merge: after this, ALL 16 col-lanes share identical m1/m2
#pragma unroll
    for (int msk = 1; msk <= 8; msk <<= 1) {
#pragma unroll
        for (int s = 0; s < 4; ++s)
#pragma unroll
            for (int r = 0; r < 4; ++r) {
                float o1 = __shfl_xor(m1[s][r], msk, 64);
                float o2 = __shfl_xor(m2[s][r], msk, 64);
                m2[s][r] = __builtin_amdgcn_fmed3f(m1[s][r], o1, fmaxf(m2[s][r], o2));
                m1[s][r] = fmaxf(m1[s][r], o1);
            }
    }

    // ---- per-lane writeout: lane handles token (s0 = col>>2, r0 = col&3, own q) ----
    const int s0 = col >> 2, r0 = col & 3;
    const int token = base_tok + s0 * 16 + q * 4 + r0;

    float m1v, m2v;
    {
        float a = pick4(m1[0][0], m1[0][1], m1[0][2], m1[0][3], r0);
        float b = pick4(m1[1][0], m1[1][1], m1[1][2], m1[1][3], r0);
        float c = pick4(m1[2][0], m1[2][1], m1[2][2], m1[2][3], r0);
        float d = pick4(m1[3][0], m1[3][1], m1[3][2], m1[3][3], r0);
        m1v = pick4(a, b, c, d, s0);
        a = pick4(m2[0][0], m2[0][1], m2[0][2], m2[0][3], r0);
        b = pick4(m2[1][0], m2[1][1], m2[1][2], m2[1][3], r0);
        c = pick4(m2[2][0], m2[2][1], m2[2][2], m2[2][3], r0);
        d = pick4(m2[3][0], m2[3][1], m2[3][2], m2[3][3], r0);
        m2v = pick4(a, b, c, d, s0);
    }
    // zsq of my token lives (for index s) on lane col==q*4+r0 (any q there)
    const int c0 = q * 4 + r0;
    float z0s = __shfl(zp[0], c0, 64);
    float z1s = __shfl(zp[1], c0, 64);
    float z2s = __shfl(zp[2], c0, 64);
    float z3s = __shfl(zp[3], c0, 64);
    const float zsqv = pick4(z0s, z1s, z2s, z3s, s0);

    const int k_sel = (int)(__float_as_uint(m1v) & 511u);
    const float dminA = fmaf(-2.0f, m1v, zsqv + 1.0f);   // ||z||^2 + 1 - 2*dot

    out_idx[token] = (float)k_sel;
    if (m1v - m2v < MARGIN_A) {
        int* rc = (int*)ws + RC_OFF;
        int pp = atomicAdd(rc, 1);
        if (pp < RMAX) {
            int* rl = (int*)ws + RLIST_OFF;
            rl[2 * pp] = token;
            rl[2 * pp + 1] = (int)__float_as_uint(dminA);
        }
    }
    atomicAdd(&hist[k_sel], 1);

    // commitment: wave-reduce dminA -> one partial per wave (plain store)
    float csum = dminA;
#pragma unroll
    for (int off = 32; off > 0; off >>= 1) csum += __shfl_down(csum, off, 64);
    if (lane == 0) ws[CPART_OFF + W] = csum;

    // z_q: gather winner row (fp32, L2-hot) and write strided (coalesced per d-plane)
    {
        const int b = token >> 12, h = (token >> 8) & 15, t = token & 255;
        const size_t zb = (size_t)b * DHT + (size_t)h * TT + (size_t)t;
        const float4* er = reinterpret_cast<const float4*>(emb + (size_t)k_sel * DD);
#pragma unroll
        for (int i = 0; i < 16; ++i) {
            float4 v = er[i];
            out_zq[zb + (size_t)(4*i+0) * HT] = v.x;
            out_zq[zb + (size_t)(4*i+1) * HT] = v.y;
            out_zq[zb + (size_t)(4*i+2) * HT] = v.z;
            out_zq[zb + (size_t)(4*i+3) * HT] = v.w;
        }
    }

    // histogram -> global (one pass per block)
    __syncthreads();
    int c = hist[tid];       if (c) atomicAdd(ws + CNT_OFF + tid,       (float)c);
    c     = hist[tid + 256]; if (c) atomicAdd(ws + CNT_OFF + tid + 256, (float)c);
}

// Rescue v2 (exact fp32 rescan of ambiguous tokens) + fused stats via last-block gate.
// Thread t caches code t's fp32 row in VGPRs ONCE -> per-token cost is only a
// 64-float z stage + 128 VALU + shuffle reduce (no per-iteration codebook traffic).
__global__ __launch_bounds__(512) void vq_rescue_stats(
    const float* __restrict__ z_e, const float* __restrict__ emb,
    float* __restrict__ ws, float* __restrict__ out, float* __restrict__ out_idx)
{
    __shared__ float lz[DD];
    __shared__ float sdw[8];
    __shared__ int   siw[8];
    __shared__ float rd;      // winning distance
    __shared__ int   ri;      // winning index
    __shared__ float sd[512];
    __shared__ int   si[512];
    __shared__ float s_com[512];
    __shared__ int   amlast;
    float* out_zq = out;
    const int tid = threadIdx.x;
    const int ln  = tid & 63, wv = tid >> 6;
    int cnt = ((const int*)ws)[RC_OFF];
    if (cnt > RMAX) cnt = RMAX;
    const int* rl = (const int*)ws + RLIST_OFF;

    // cache my code's row (code = tid) in registers — read once per block
    float4 er[16];
    {
        const float4* erp = reinterpret_cast<const float4*>(emb + (size_t)tid * DD);
#pragma unroll
        for (int i = 0; i < 16; ++i) er[i] = erp[i];
    }

    for (int it = blockIdx.x; it < cnt; it += gridDim.x) {
        const int n = rl[2 * it];
        const float dminA = __uint_as_float((unsigned)rl[2 * it + 1]);
        const int b = n >> 12, h = (n >> 8) & 15;
        const size_t zoff = (size_t)b * DHT + (size_t)h * 256 + (size_t)(n & 255);
        __syncthreads();
        if (tid < DD) lz[tid] = z_e[zoff + (size_t)tid * HT];
        __syncthreads();
        float a0 = 0.f, a1 = 0.f, a2 = 0.f, a3 = 0.f;
#pragma unroll
        for (int i = 0; i < 16; ++i) {
            float4 e4 = er[i];
            float d0 = lz[4*i+0] - e4.x; a0 = fmaf(d0, d0, a0);
            float d1 = lz[4*i+1] - e4.y; a1 = fmaf(d1, d1, a1);
            float d2 = lz[4*i+2] - e4.z; a2 = fmaf(d2, d2, a2);
            float d3 = lz[4*i+3] - e4.w; a3 = fmaf(d3, d3, a3);
        }
        float dmin = (a0 + a1) + (a2 + a3);
        int   kmin = tid;
        // wave reduce (min, lowest-index tie-break)
#pragma unroll
        for (int off = 32; off > 0; off >>= 1) {
            float od = __shfl_xor(dmin, off, 64);
            int   oi = __shfl_xor(kmin, off, 64);
            if (od < dmin || (od == dmin && oi < kmin)) { dmin = od; kmin = oi; }
        }
        if (ln == 0) { sdw[wv] = dmin; siw[wv] = kmin; }
        __syncthreads();
        if (tid == 0) {
            float bd = sdw[0]; int bi = siw[0];
#pragma unroll
            for (int w = 1; w < 8; ++w) {
                float d2 = sdw[w]; int j2 = siw[w];
                if (d2 < bd || (d2 == bd && j2 < bi)) { bd = d2; bi = j2; }
            }
            rd = bd; ri = bi;
            const int k_old = (int)out_idx[n];
            atomicAdd(ws + CDELTA_OFF, bd - dminA);   // exact commitment correction
            if (bi != k_old) {
                out_idx[n] = (float)bi;
                atomicAdd(ws + CNT_OFF + k_old, -1.0f);
                atomicAdd(ws + CNT_OFF + bi,    1.0f);
            }
            ri = (bi != k_old) ? bi : -1;
        }
        __syncthreads();
        const int k_new = ri;
        if (k_new >= 0 && tid < DD)
            out_zq[zoff + (size_t)tid * HT] = emb[(size_t)k_new * DD + tid];
    }

    // ---- gate: last block to finish runs the stats reduction ----
    __threadfence();
    if (tid == 0) {
        int d = atomicAdd((int*)ws + DONE_OFF, 1);
        amlast = (d == (int)gridDim.x - 1) ? 1 : 0;
    }
    __syncthreads();
    if (!amlast) return;

    // stats: counts/cdelta were atomically updated within this kernel -> agent-scope loads
    const int k = tid;
    const float c = __hip_atomic_load(ws + CNT_OFF + k, __ATOMIC_RELAXED, __HIP_MEMORY_SCOPE_AGENT);
    const float p = c * (1.0f / (float)NN);
    sd[k]    = p * logf(p + 1e-12f);
    si[k]    = (p > 0.0f) ? 1 : 0;
    s_com[k] = ws[CPART_OFF + k] + ws[CPART_OFF + 512 + k]
             + ws[CPART_OFF + 1024 + k] + ws[CPART_OFF + 1536 + k];
    __syncthreads();
    for (int off = 256; off > 0; off >>= 1) {
        if (k < off) {
            sd[k]    += sd[k + off];
            si[k]    += si[k + off];
            s_com[k] += s_com[k + off];
        }
        __syncthreads();
    }
    if (k == 0) {
        float cdelta = __hip_atomic_load(ws + CDELTA_OFF, __ATOMIC_RELAXED, __HIP_MEMORY_SCOPE_AGENT);
        out[COMMIT_OFF] = 0.25f * (s_com[0] + cdelta) / (float)ZQ_SIZE;
        out[PPL_OFF]    = expf(-sd[0]);
        out[USE_OFF]    = (float)si[0] / (float)KK;
    }
}

extern "C" void kernel_launch(void* const* d_in, const int* in_sizes, int n_in,
                              void* d_out, int out_size, void* d_ws, size_t ws_size,
                              hipStream_t stream) {
    const float* z_e = (const float*)d_in[0];
    const float* emb = (const float*)d_in[1];
    float* out = (float*)d_out;
    float* ws  = (float*)d_ws;

    float* out_idx = out + IDX_OFF;

    vq_init<<<32, 256, 0, stream>>>(emb, ws);
    vq_screen<<<512, 256, 0, stream>>>(z_e, emb, ws, out, out_idx);
    vq_rescue_stats<<<512, 512, 0, stream>>>(z_e, emb, ws, out, out_idx);
}